// Round 2
// baseline (160.640 us; speedup 1.0000x reference)
//
#include <hip/hip_runtime.h>

#define POS_IN 63
#define HID 128
#define TOTAL 8789
#define NB 32
#define NPTS 65536

#define PB_OFF 8064
#define SW_OFF 8192
#define SB_OFF 8320
#define CW_OFF 8321
#define CB_OFF 8786

#define BLOCKS_PER_BATCH 16
#define PTS_PER_BLOCK (NPTS / BLOCKS_PER_BATCH) /* 4096 */
#define ITERS (PTS_PER_BLOCK / 256)             /* 16 */

typedef __attribute__((ext_vector_type(8))) short s16x8;
typedef __attribute__((ext_vector_type(4))) float f32x4;

// f32 -> bf16 (round-to-nearest-even), pure integer ops (finite inputs only)
__device__ __forceinline__ unsigned short f2bf(float v) {
    unsigned u = __builtin_bit_cast(unsigned, v);
    unsigned r = 0x7fffu + ((u >> 16) & 1u);
    return (unsigned short)((u + r) >> 16);
}
__device__ __forceinline__ unsigned pk2(float a, float b) {
    return (unsigned)f2bf(a) | ((unsigned)f2bf(b) << 16);
}

__global__ __launch_bounds__(256, 2) void nerf_mlp_kernel(
        const float* __restrict__ params,
        const float* __restrict__ points,
        const float* __restrict__ dirs,
        float* __restrict__ out)
{
    // LDS: bytes [0,32768) = per-wave enc buffers (8KB each), aliased at start
    // by the pw bf16 stage ([128][72] ushort = 18432B). [32768,36864) = colpart.
    __shared__ __align__(16) unsigned char smem[36864];
    unsigned short* stage = (unsigned short*)smem;

    const int tid = threadIdx.x;
    const int lane = tid & 63;
    const int wid = tid >> 6;
    const int b = blockIdx.y;
    const float* P = params + (size_t)b * TOTAL;

    // ---- stage pw (128x63 f32) into LDS as bf16, row stride 72, pad k=63 with 0
    for (int idx = tid; idx < 8064; idx += 256) {
        int n = idx / 63;
        int k = idx - n * 63;
        stage[n * 72 + k] = f2bf(P[idx]);
        if (k == 0) stage[n * 72 + 63] = 0;
    }
    __syncthreads();

    const int c = lane & 15;   // col-in-tile (h index low bits / point-in-tile)
    const int kg = lane >> 4;  // k-group 0..3

    // ---- build 16 persistent B fragments (pw^T), layout: lane holds
    // B[k=(kh*32)+kg*8 .. +8][n=nt*16+c]  = pw[n][k..k+7] (contiguous)
    s16x8 wB[8][2];
    #pragma unroll
    for (int nt = 0; nt < 8; ++nt) {
        #pragma unroll
        for (int kh = 0; kh < 2; ++kh) {
            int n = nt * 16 + c;
            int k = kh * 32 + kg * 8;
            uint4 raw = *(const uint4*)&stage[n * 72 + k];
            wB[nt][kh] = __builtin_bit_cast(s16x8, raw);
        }
    }
    __syncthreads();   // stage area now reusable as enc buffers

    // ---- per-lane persistent epilogue weights (index depends only on c)
    float pb_v[8], sw_v[8], cw0_v[8], cw1_v[8], cw2_v[8];
    #pragma unroll
    for (int nt = 0; nt < 8; ++nt) {
        int hh = nt * 16 + c;
        pb_v[nt]  = P[PB_OFF + hh];
        sw_v[nt]  = P[SW_OFF + hh];
        cw0_v[nt] = P[CW_OFF + 0 * 155 + hh];
        cw1_v[nt] = P[CW_OFF + 1 * 155 + hh];
        cw2_v[nt] = P[CW_OFF + 2 * 155 + hh];
    }
    const int oo = lane & 3;          // output channel this lane stores
    const int jj = (lane & 15) >> 2;  // point-reg this lane stores
    const float cbias = P[oo < 3 ? (CB_OFF + oo) : SB_OFF];

    unsigned char* encb = smem + wid * 8192;            // [kq][p][8] bf16
    float* cpb = (float*)(smem + 32768 + wid * 1024);   // [64][4] f32 colpart

    const size_t bpts = (size_t)b * NPTS;
    const int n0b = blockIdx.x * PTS_PER_BLOCK;

    for (int it = 0; it < ITERS; ++it) {
        const int n0 = n0b + it * 256 + wid * 64;  // this wave's 64-point chunk
        const int p = n0 + lane;

        const float* pp = points + (bpts + p) * 3;
        float x = pp[0], y = pp[1], z = pp[2];
        const float* dd = dirs + (bpts + p) * 3;
        float dx = dd[0], dy = dd[1], dz = dd[2];

        // ---- positional encoding (63 + 1 pad), sincos via angle doubling
        float e[64];
        e[0] = x; e[1] = y; e[2] = z; e[63] = 0.f;
        #pragma unroll
        for (int i = 0; i < 3; ++i) {
            float v = (i == 0) ? x : (i == 1) ? y : z;
            float s = __sinf(v), co = __cosf(v);
            e[3 + i * 10] = s; e[33 + i * 10] = co;
            #pragma unroll
            for (int f = 1; f < 10; ++f) {
                float ns = 2.f * s * co;
                float nc = 1.f - 2.f * s * s;
                s = ns; co = nc;
                e[3 + i * 10 + f] = s;
                e[33 + i * 10 + f] = co;
            }
        }

        // ---- dir encoding folded directly into color partials (SGPR weights)
        float cp0 = 0.f, cp1 = 0.f, cp2 = 0.f;
        #pragma unroll
        for (int i = 0; i < 3; ++i) {
            float v = (i == 0) ? dx : (i == 1) ? dy : dz;
            cp0 = fmaf(v, P[CW_OFF + 128 + i], cp0);
            cp1 = fmaf(v, P[CW_OFF + 155 + 128 + i], cp1);
            cp2 = fmaf(v, P[CW_OFF + 310 + 128 + i], cp2);
            float s = __sinf(v), co = __cosf(v);
            #pragma unroll
            for (int f = 0; f < 4; ++f) {
                if (f > 0) {
                    float ns = 2.f * s * co;
                    float nc = 1.f - 2.f * s * s;
                    s = ns; co = nc;
                }
                int si = 128 + 3 + i * 4 + f;
                int ci = 128 + 15 + i * 4 + f;
                cp0 = fmaf(s, P[CW_OFF + si], cp0);
                cp1 = fmaf(s, P[CW_OFF + 155 + si], cp1);
                cp2 = fmaf(s, P[CW_OFF + 310 + si], cp2);
                cp0 = fmaf(co, P[CW_OFF + ci], cp0);
                cp1 = fmaf(co, P[CW_OFF + 155 + ci], cp1);
                cp2 = fmaf(co, P[CW_OFF + 310 + ci], cp2);
            }
        }
        *(float4*)(cpb + lane * 4) = make_float4(cp0, cp1, cp2, 0.f);

        // ---- pack enc to LDS (bf16), layout [kq][point][8]
        #pragma unroll
        for (int kq = 0; kq < 8; ++kq) {
            uint4 q;
            q.x = pk2(e[kq * 8 + 0], e[kq * 8 + 1]);
            q.y = pk2(e[kq * 8 + 2], e[kq * 8 + 3]);
            q.z = pk2(e[kq * 8 + 4], e[kq * 8 + 5]);
            q.w = pk2(e[kq * 8 + 6], e[kq * 8 + 7]);
            *(uint4*)(encb + kq * 1024 + lane * 16) = q;
        }

        float* outp = out + (bpts + n0) * 4;

        // ---- 4 m-tiles of 16 points
        #pragma unroll
        for (int t = 0; t < 4; ++t) {
            uint4 a0r = *(const uint4*)(encb + kg * 1024 + (t * 16 + c) * 16);
            uint4 a1r = *(const uint4*)(encb + (4 + kg) * 1024 + (t * 16 + c) * 16);
            s16x8 A0 = __builtin_bit_cast(s16x8, a0r);
            s16x8 A1 = __builtin_bit_cast(s16x8, a1r);

            f32x4 acc[8];
            #pragma unroll
            for (int nt = 0; nt < 8; ++nt) {
                acc[nt] = (f32x4){pb_v[nt], pb_v[nt], pb_v[nt], pb_v[nt]}; // bias folded
                acc[nt] = __builtin_amdgcn_mfma_f32_16x16x32_bf16(A0, wB[nt][0], acc[nt], 0, 0, 0);
                acc[nt] = __builtin_amdgcn_mfma_f32_16x16x32_bf16(A1, wB[nt][1], acc[nt], 0, 0, 0);
            }

            // D layout: col = nt*16 + (lane&15) = h index, row = kg*4 + j = point
            float sg[4] = {0,0,0,0}, c0[4] = {0,0,0,0}, c1[4] = {0,0,0,0}, c2[4] = {0,0,0,0};
            #pragma unroll
            for (int j = 0; j < 4; ++j) {
                #pragma unroll
                for (int nt = 0; nt < 8; ++nt) {
                    float hv = fmaxf(acc[nt][j], 0.f);   // relu(h + pb)
                    sg[j] = fmaf(hv, sw_v[nt], sg[j]);
                    c0[j] = fmaf(hv, cw0_v[nt], c0[j]);
                    c1[j] = fmaf(hv, cw1_v[nt], c1[j]);
                    c2[j] = fmaf(hv, cw2_v[nt], c2[j]);
                }
            }
            // 16-lane butterfly reduction (stays within lane group kg)
            #pragma unroll
            for (int m = 1; m <= 8; m <<= 1) {
                #pragma unroll
                for (int j = 0; j < 4; ++j) {
                    sg[j] += __shfl_xor(sg[j], m, 64);
                    c0[j] += __shfl_xor(c0[j], m, 64);
                    c1[j] += __shfl_xor(c1[j], m, 64);
                    c2[j] += __shfl_xor(c2[j], m, 64);
                }
            }
            // lane (kg, jj, oo) -> point t*16+kg*4+jj, channel oo
            float a0 = (oo == 0) ? c0[0] : (oo == 1) ? c1[0] : (oo == 2) ? c2[0] : sg[0];
            float a1 = (oo == 0) ? c0[1] : (oo == 1) ? c1[1] : (oo == 2) ? c2[1] : sg[1];
            float a2 = (oo == 0) ? c0[2] : (oo == 1) ? c1[2] : (oo == 2) ? c2[2] : sg[2];
            float a3 = (oo == 0) ? c0[3] : (oo == 1) ? c1[3] : (oo == 2) ? c2[3] : sg[3];
            float val = (jj == 0) ? a0 : (jj == 1) ? a1 : (jj == 2) ? a2 : a3;

            val += cpb[t * 64 + lane] + cbias;  // dir-branch of color (0 for sigma) + bias
            float sig = 1.f / (1.f + __expf(-val));
            val = (oo < 3) ? sig : val;         // sigmoid on color only

            outp[t * 64 + lane] = val;          // fully coalesced: offset = t*64+lane
        }
    }
}

extern "C" void kernel_launch(void* const* d_in, const int* in_sizes, int n_in,
                              void* d_out, int out_size, void* d_ws, size_t ws_size,
                              hipStream_t stream) {
    const float* params = (const float*)d_in[0];
    const float* points = (const float*)d_in[1];
    const float* dirs   = (const float*)d_in[2];
    float* out = (float*)d_out;
    dim3 grid(BLOCKS_PER_BATCH, NB);
    nerf_mlp_kernel<<<grid, 256, 0, stream>>>(params, points, dirs, out);
}